// Round 7
// baseline (559.255 us; speedup 1.0000x reference)
//
#include <hip/hip_runtime.h>
#include <stdint.h>

// Problem constants (N,C,H,W) = (32,256,56,56), 3x3 conv pad=1 stride=1
#define NB    32
#define C     256
#define HH    56
#define WW    56
#define HW    3136        // 56*56
#define P_TOT 100352      // NB*HW
#define PW    58          // halo-padded width
#define PHW   3364        // 58*58
#define NPAD  107648      // NB*PHW
#define EPSBN 1e-5f

#define KEEP9(a) asm volatile("" :: "v"(a[0]), "v"(a[1]), "v"(a[2]), "v"(a[3]), \
    "v"(a[4]), "v"(a[5]), "v"(a[6]), "v"(a[7]), "v"(a[8]))

// ---------------- 64-lane u64 shuffle + 64x64 bit-matrix transpose -----------
__device__ __forceinline__ uint64_t shflx64(uint64_t v, int m) {
    int lo = __shfl_xor((int)(uint32_t)v, m, 64);
    int hi = __shfl_xor((int)(uint32_t)(v >> 32), m, 64);
    return ((uint64_t)(uint32_t)hi << 32) | (uint32_t)lo;
}
// Input: lane i holds bits j. Output: lane j holds bits i.
__device__ __forceinline__ uint64_t bt64(uint64_t M, int lane) {
    const uint64_t mk[6] = {0x5555555555555555ULL, 0x3333333333333333ULL,
                            0x0F0F0F0F0F0F0F0FULL, 0x00FF00FF00FF00FFULL,
                            0x0000FFFF0000FFFFULL, 0x00000000FFFFFFFFULL};
#pragma unroll
    for (int k = 0; k < 6; ++k) {
        int s = 1 << k;
        uint64_t mA = mk[k];
        uint64_t v = shflx64(M, s);
        M = (lane & s) ? ((M & ~mA) | ((v & ~mA) >> s))
                       : ((M &  mA) | ((v &  mA) << s));
    }
    return M;
}

// ============ pack weights (both sets) via ballot: 1 wave per (set,co,t,wd) ==
// pwt layout: [co][40] u64, slot wd*9+t (contiguous 288B/co -> s_load_dwordx16)
__global__ __launch_bounds__(256) void pack_wgt(const float* __restrict__ w1,
                                                const float* __restrict__ w2,
                                                uint64_t* __restrict__ pw1,
                                                uint64_t* __restrict__ pw2,
                                                int* __restrict__ pc1,
                                                int* __restrict__ pc2) {
    int gw = blockIdx.x * 4 + (threadIdx.x >> 6);   // global wave 0..18431
    int lane = threadIdx.x & 63;
    int set = gw / 9216;
    int r = gw - set * 9216;
    int wd = r & 3, q = r >> 2;
    int t = q % 9, co = q / 9;
    const float* w = set ? w2 : w1;
    float v = w[(size_t)co * 2304 + (size_t)(wd * 64 + lane) * 9 + t];
    unsigned long long m = __ballot(v >= 0.0f);
    if (lane == 0) {
        uint64_t* pw = set ? pw2 : pw1;
        int* pc = set ? pc2 : pc1;
        pw[(size_t)co * 40 + wd * 9 + t] = m;
        pc[(co * 9 + t) * 4 + wd] = (int)__popcll(m);
    }
}

// ====== border-correction: K[pat][co] = 256*Tvalid + 2*sum_{t inv} popc(w_t) =
__global__ __launch_bounds__(256) void build_K(const int* __restrict__ pc1,
                                               const int* __restrict__ pc2,
                                               unsigned short* __restrict__ K1,
                                               unsigned short* __restrict__ K2) {
    int tid = blockIdx.x * 256 + threadIdx.x;       // 0..4607
    int set = tid / 2304;
    int r = tid - set * 2304;
    int pat = r >> 8, co = r & 255;
    int pv = pat / 3, pq = pat - pv * 3;
    const int* pc = set ? pc2 : pc1;
    int k = 0, corr = 0;
#pragma unroll
    for (int t = 0; t < 9; ++t) {
        int ty = t / 3, tx = t - ty * 3;
        bool inv = (pv == 0 && ty == 0) || (pv == 2 && ty == 2) ||
                   (pq == 0 && tx == 0) || (pq == 2 && tx == 2);
        if (inv) {
            ++k;
            const int* p = pc + (co * 9 + t) * 4;
            corr += p[0] + p[1] + p[2] + p[3];
        }
    }
    unsigned short* K = set ? K2 : K1;
    K[pat * 256 + co] = (unsigned short)(256 * (9 - k) + 2 * corr);
}

// ==== pack activations (ballot+transpose) + zero halos of BOTH px buffers ====
__global__ __launch_bounds__(256) void pack_act(const float* __restrict__ x,
                                                uint64_t* __restrict__ px1,
                                                uint64_t* __restrict__ px2) {
    if (blockIdx.x >= 1568) {                       // halo zeroing mode
        int u = (blockIdx.x - 1568) * 256 + threadIdx.x;   // 0..29183
        if (u >= 29184) return;
        int wd = u & 3, v = u >> 2;                 // v = n*228 + cell
        int n = v / 228, cell = v - n * 228;
        int ph, pw_;
        if (cell < 58)       { ph = 0;          pw_ = cell; }
        else if (cell < 116) { ph = 57;         pw_ = cell - 58; }
        else if (cell < 172) { ph = cell - 115; pw_ = 0; }
        else                 { ph = cell - 171; pw_ = 57; }
        size_t idx = (size_t)wd * NPAD + (size_t)n * PHW + (size_t)ph * PW + pw_;
        px1[idx] = 0ull;
        px2[idx] = 0ull;
        return;
    }
    int wid = blockIdx.x * 4 + (threadIdx.x >> 6);  // 0..6271
    int lane = threadIdx.x & 63;
    int wd = wid & 3;
    int g = wid >> 2;                               // 0..1567
    int n = g / 49, gi = g - n * 49;
    const float* xp = x + ((size_t)n * C + wd * 64) * HW + gi * 64 + lane;
    uint64_t M = 0;
#pragma unroll
    for (int c = 0; c < 64; ++c) {
        float v = xp[(size_t)c * HW];
        unsigned long long m = __ballot(v >= 0.0f);
        if (lane == c) M = m;
    }
    M = bt64(M, lane);                              // lane p: bit c = sign
    int p = gi * 64 + lane;
    int h = p / WW, w = p - h * WW;
    px1[(size_t)wd * NPAD + (size_t)n * PHW + (size_t)(h + 1) * PW + (w + 1)] = M;
}

// ========== binary conv: thread = pixel, loop over co (wave-uniform) =========
// Taps: 36 u64 per-lane VGPRs (pinned). Weights: s_load from [co][40].
// Output planar s16[c][p], coalesced 128B stores.
__global__ __launch_bounds__(256, 2) void bconv(const uint64_t* __restrict__ px,
                                                const uint64_t* __restrict__ pwt,
                                                const unsigned short* __restrict__ Kt,
                                                short* __restrict__ sout) {
    __shared__ unsigned short Kl[2304];
#pragma unroll 1
    for (int i = threadIdx.x; i < 2304; i += 256) Kl[i] = Kt[i];

    int p = blockIdx.x * 256 + threadIdx.x;
    int n = p / HW, rem = p - n * HW;
    int h = rem / WW, w = rem - h * WW;
    size_t base = (size_t)n * PHW + (size_t)(h + 1) * PW + (w + 1);

    uint64_t xt[36];
#pragma unroll
    for (int wd = 0; wd < 4; ++wd) {
        const uint64_t* xb = px + (size_t)wd * NPAD + base;
        xt[wd * 9 + 0] = xb[-PW - 1]; xt[wd * 9 + 1] = xb[-PW]; xt[wd * 9 + 2] = xb[-PW + 1];
        xt[wd * 9 + 3] = xb[-1];      xt[wd * 9 + 4] = xb[0];   xt[wd * 9 + 5] = xb[1];
        xt[wd * 9 + 6] = xb[PW - 1];  xt[wd * 9 + 7] = xb[PW];  xt[wd * 9 + 8] = xb[PW + 1];
    }
    __syncthreads();

    int pv = (h == 0) ? 0 : ((h == HH - 1) ? 2 : 1);
    int pq = (w == 0) ? 0 : ((w == WW - 1) ? 2 : 1);
    const unsigned short* Krow = Kl + ((pv * 3 + pq) << 8);

    int co0 = blockIdx.y * 64;
    short* op = sout + (size_t)co0 * P_TOT + p;
#pragma unroll 2
    for (int c = 0; c < 64; ++c) {
        const uint64_t* wq = pwt + (size_t)(co0 + c) * 40;
        // keep the 36 taps register-resident across the whole co loop
        KEEP9((xt + 0)); KEEP9((xt + 9)); KEEP9((xt + 18)); KEEP9((xt + 27));
        int a0 = 0, a1 = 0, a2 = 0, a3 = 0;
#pragma unroll
        for (int t = 0; t < 9; ++t) {
            a0 += __popcll(xt[t]      ^ wq[t]);
            a1 += __popcll(xt[9 + t]  ^ wq[9 + t]);
            a2 += __popcll(xt[18 + t] ^ wq[18 + t]);
            a3 += __popcll(xt[27 + t] ^ wq[27 + t]);
        }
        int dot = (int)Krow[co0 + c] - 2 * (a0 + a1 + a2 + a3);
        op[(size_t)c * P_TOT] = (short)dot;
    }
}

// ==== BN stats from planar s16[c][p] + fused A/B finalize (one block/chan) ===
// y = dot*A[c] + B[c]  with  A = 0.5*g*rsqrt(var+eps), B = b - m*(2A)
__global__ __launch_bounds__(256) void statsAB(const short* __restrict__ s,
                                               const float* __restrict__ g,
                                               const float* __restrict__ b,
                                               float* __restrict__ A,
                                               float* __restrict__ Bv) {
    int c = blockIdx.x;
    const int4* sp = (const int4*)(s + (size_t)c * P_TOT);
    int sum = 0;
    long long sqq = 0;
#pragma unroll 4
    for (int i = threadIdx.x; i < 12544; i += 256) {      // 12544 = P_TOT/8
        int4 v = sp[i];
        int sq8 = 0;
#pragma unroll
        for (int j = 0; j < 4; ++j) {
            int u = (&v.x)[j];
            int s0 = (int)(short)(u & 0xFFFF);
            int s1 = u >> 16;
            sum += s0 + s1;
            sq8 += s0 * s0 + s1 * s1;
        }
        sqq += sq8;
    }
    long long lsum = sum;
#pragma unroll
    for (int off = 32; off; off >>= 1) {
        lsum += __shfl_down(lsum, off, 64);
        sqq  += __shfl_down(sqq,  off, 64);
    }
    __shared__ long long r0[4], r1[4];
    int lane = threadIdx.x & 63, wv = threadIdx.x >> 6;
    if (lane == 0) { r0[wv] = lsum; r1[wv] = sqq; }
    __syncthreads();
    if (threadIdx.x == 0) {
        long long S = r0[0] + r0[1] + r0[2] + r0[3];
        long long Q = r1[0] + r1[1] + r1[2] + r1[3];
        float m  = 0.5f  * (float)S / (float)P_TOT;
        float e2 = 0.25f * (float)Q / (float)P_TOT;
        float var = e2 - m * m;
        float a = g[c] * rsqrtf(var + EPSBN);
        A[c]  = 0.5f * a;
        Bv[c] = b[c] - m * a;
    }
}

// ==== bn1 + sign + repack: ballot over coalesced planar loads + transpose ====
__global__ __launch_bounds__(256) void bnpack(const short* __restrict__ s,
                                              const float* __restrict__ A,
                                              const float* __restrict__ Bv,
                                              uint64_t* __restrict__ px) {
    int wid = blockIdx.x * 4 + (threadIdx.x >> 6);  // 0..6271
    int lane = threadIdx.x & 63;
    int wd = wid & 3;
    int g = wid >> 2;                               // 0..1567
    const short* sp = s + (size_t)(wd * 64) * P_TOT + g * 64 + lane;
    uint64_t M = 0;
#pragma unroll
    for (int c = 0; c < 64; ++c) {
        float y = (float)sp[(size_t)c * P_TOT] * A[wd * 64 + c] + Bv[wd * 64 + c];
        unsigned long long m = __ballot(y >= 0.0f);
        if (lane == c) M = m;
    }
    M = bt64(M, lane);
    int p = g * 64 + lane;
    int n = p / HW, rem = p - n * HW;
    int h = rem / WW, w = rem - h * WW;
    px[(size_t)wd * NPAD + (size_t)n * PHW + (size_t)(h + 1) * PW + (w + 1)] = M;
}

// ======= bn2 + shortcut + hardtanh: planar everywhere, fully coalesced =======
__global__ __launch_bounds__(256) void finalize(const short* __restrict__ s,
                                                const float* __restrict__ x,
                                                const float* __restrict__ A,
                                                const float* __restrict__ Bv,
                                                float* __restrict__ out) {
    int i = blockIdx.x * 256 + threadIdx.x;       // group of 4 over [c][n][hw]
    int c = i / 25088;                            // 25088 = P_TOT/4
    int r4 = i - c * 25088;
    int n = r4 / 784, hw4 = r4 - n * 784;         // 784 = HW/4
    short4 sv = ((const short4*)s)[i];
    size_t gx = (size_t)(n * C + c) * 784 + hw4;
    float4 xv = ((const float4*)x)[gx];
    float a = A[c], bb = Bv[c];
    float4 o;
    o.x = fminf(1.0f, fmaxf(-1.0f, (float)sv.x * a + bb + xv.x));
    o.y = fminf(1.0f, fmaxf(-1.0f, (float)sv.y * a + bb + xv.y));
    o.z = fminf(1.0f, fmaxf(-1.0f, (float)sv.z * a + bb + xv.z));
    o.w = fminf(1.0f, fmaxf(-1.0f, (float)sv.w * a + bb + xv.w));
    ((float4*)out)[gx] = o;
}

extern "C" void kernel_launch(void* const* d_in, const int* in_sizes, int n_in,
                              void* d_out, int out_size, void* d_ws, size_t ws_size,
                              hipStream_t stream) {
    const float* x  = (const float*)d_in[0];
    const float* w1 = (const float*)d_in[1];
    const float* g1 = (const float*)d_in[2];
    const float* b1 = (const float*)d_in[3];
    const float* w2 = (const float*)d_in[4];
    const float* g2 = (const float*)d_in[5];
    const float* b2 = (const float*)d_in[6];
    float* out = (float*)d_out;

    // workspace layout (~58.5 MB)
    char* ws = (char*)d_ws;
    uint64_t* pwt1 = (uint64_t*)ws;           ws += 256 * 40 * 8;          // 81,920
    uint64_t* pwt2 = (uint64_t*)ws;           ws += 256 * 40 * 8;
    int* pc1 = (int*)ws;                      ws += 9216 * 4;              // 36,864
    int* pc2 = (int*)ws;                      ws += 9216 * 4;
    unsigned short* K1 = (unsigned short*)ws; ws += 8192;
    unsigned short* K2 = (unsigned short*)ws; ws += 8192;
    float* A1 = (float*)ws;                   ws += 1024;
    float* B1 = (float*)ws;                   ws += 1024;
    float* A2 = (float*)ws;                   ws += 1024;
    float* B2 = (float*)ws;                   ws += 1024;
    uint64_t* px1 = (uint64_t*)ws;            ws += (size_t)4 * NPAD * 8;  // 3,444,736
    uint64_t* px2 = (uint64_t*)ws;            ws += (size_t)4 * NPAD * 8;
    short* s16 = (short*)ws;                  // 51,380,224, planar [c][P_TOT]

    pack_wgt<<<4608, 256, 0, stream>>>(w1, w2, pwt1, pwt2, pc1, pc2);
    build_K<<<18, 256, 0, stream>>>(pc1, pc2, K1, K2);
    pack_act<<<1568 + 114, 256, 0, stream>>>(x, px1, px2);

    bconv<<<dim3(392, 4), 256, 0, stream>>>(px1, pwt1, K1, s16);
    statsAB<<<C, 256, 0, stream>>>(s16, g1, b1, A1, B1);
    bnpack<<<1568, 256, 0, stream>>>(s16, A1, B1, px2);

    bconv<<<dim3(392, 4), 256, 0, stream>>>(px2, pwt2, K2, s16);
    statsAB<<<C, 256, 0, stream>>>(s16, g2, b2, A2, B2);

    finalize<<<(P_TOT * C / 4) / 256, 256, 0, stream>>>(s16, x, A2, B2, out);
}